// Round 10
// baseline (158.194 us; speedup 1.0000x reference)
//
#include <hip/hip_runtime.h>

#define NB 4096
#define MM 128
#define NN 96
#define LL 20
#define UTS 72   // Ut row stride in u16 (144B, b128-aligned)

typedef __attribute__((ext_vector_type(8))) short bf16x8;
typedef __attribute__((ext_vector_type(4))) float f32x4;
typedef __attribute__((ext_vector_type(4))) unsigned int u32x4;

__device__ __forceinline__ unsigned short rne16(float f) {
    unsigned u = __float_as_uint(f);
    return (unsigned short)((u + 0x7fffu + ((u >> 16) & 1u)) >> 16);
}
__device__ __forceinline__ unsigned pack2(float a, float b) {
    return (unsigned)rne16(a) | ((unsigned)rne16(b) << 16);
}

// Block = 128 threads (2 waves) = 1 batch.
// Phase A: both waves stage Ht cooperatively; wave w computes HTH J-tiles
//   {3w,3w+1,3w+2} (acc[6][3], 72 AGPR) + HTy via broadcast-y frag (accY[6]).
// Transition: per-wave in-register bpermute transpose -> afr rows 3w..3w+2
//   (R9-verified formula; each wave holds all ktile indices under J-split).
// Phase B: wave w owns rows 48w..48w+47: 9 MFMA/iter, double-buffered yx,
//   ONE barrier per iteration.
__global__ __launch_bounds__(128) __attribute__((amdgpu_waves_per_eu(3)))
void pg_kernel(const float* __restrict__ x_ini,
               const float* __restrict__ y,
               const float* __restrict__ H,
               const float* __restrict__ xt,
               const float* __restrict__ grad_ss,
               const float* __restrict__ extra_ss,
               const float* __restrict__ gamma1,
               float* __restrict__ out)
{
    __shared__ __align__(16) unsigned short Ut[97 * UTS];  // Ht bf16, row c = H col c; row 96 = y
    __shared__ __align__(16) unsigned yxD[2][48];          // packed bf16 yx, double-buffered
    __shared__ __align__(16) float htyL[NN];
    __shared__ float par[3][LL];

    const int b    = blockIdx.x;
    const int tid  = threadIdx.x;
    const int lane = tid & 63;
    const int wid  = tid >> 6;
    const int m15  = lane & 15;
    const int g4   = lane >> 4;

    if (tid < LL) {
        par[0][tid] = grad_ss[tid];
        par[1][tid] = extra_ss[tid];
        par[2][tid] = gamma1[tid];
    }

    // ================= Phase A: HTH J-chunk + HTy (single-pass bf16 MFMA) =================
    f32x4 acc[6][3];   // [ktile][Jlocal]; this wave's J = wid*3 + Jlocal
    f32x4 accY[6];     // HTy via broadcast-y B-frag (both waves compute; balanced)
    #pragma unroll
    for (int kt = 0; kt < 6; ++kt) {
        #pragma unroll
        for (int jl = 0; jl < 3; ++jl)
            #pragma unroll
            for (int r = 0; r < 4; ++r) acc[kt][jl][r] = 0.f;
        #pragma unroll
        for (int r = 0; r < 4; ++r) accY[kt][r] = 0.f;
    }

    const float* Hb  = H + (size_t)b * (MM * NN);
    const int    r64 = tid >> 1;     // H row within k-half
    const int    qh  = tid & 1;      // 48-col half

    for (int kh = 0; kh < 2; ++kh) {
        if (kh) __syncthreads();     // half-0 frag reads complete before restage
        {
            const float* src = Hb + (size_t)(kh * 64 + r64) * NN + qh * 48;
            #pragma unroll
            for (int c4 = 0; c4 < 3; ++c4) {       // 3 chunks of 4 float4 (small reg window)
                float4 v[4];
                #pragma unroll
                for (int i = 0; i < 4; ++i) v[i] = *(const float4*)(src + c4 * 16 + 4 * i);
                #pragma unroll
                for (int i = 0; i < 4; ++i) {
                    const int c = qh * 48 + c4 * 16 + 4 * i;
                    Ut[(c + 0) * UTS + r64] = rne16(v[i].x);
                    Ut[(c + 1) * UTS + r64] = rne16(v[i].y);
                    Ut[(c + 2) * UTS + r64] = rne16(v[i].z);
                    Ut[(c + 3) * UTS + r64] = rne16(v[i].w);
                }
            }
            if (tid < 64) Ut[96 * UTS + tid] = rne16(y[(size_t)b * MM + kh * 64 + tid]);
        }
        __syncthreads();

        #pragma unroll
        for (int s = 0; s < 2; ++s) {              // two K=32 steps per half
            const int ko = s * 32 + g4 * 8;
            bf16x8 frB[3];
            #pragma unroll
            for (int jl = 0; jl < 3; ++jl)
                frB[jl] = *(const bf16x8*)&Ut[((wid * 3 + jl) * 16 + m15) * UTS + ko];
            bf16x8 frY = *(const bf16x8*)&Ut[96 * UTS + ko];   // broadcast: all lanes read row 96
            #pragma unroll
            for (int kt = 0; kt < 6; ++kt) {
                bf16x8 fa = *(const bf16x8*)&Ut[(kt * 16 + m15) * UTS + ko];
                #pragma unroll
                for (int jl = 0; jl < 3; ++jl)
                    acc[kt][jl] = __builtin_amdgcn_mfma_f32_16x16x32_bf16(fa, frB[jl], acc[kt][jl], 0, 0, 0);
                accY[kt] = __builtin_amdgcn_mfma_f32_16x16x32_bf16(fa, frY, accY[kt], 0, 0, 0);
            }
        }
    }

    // ====== Transition: acc -> phase-B A-frags (R9-verified symmetry + quad bpermute) ======
    unsigned pk[6][3][2];
    #pragma unroll
    for (int kt = 0; kt < 6; ++kt)
        #pragma unroll
        for (int jl = 0; jl < 3; ++jl) {
            pk[kt][jl][0] = pack2(acc[kt][jl][0], acc[kt][jl][1]);
            pk[kt][jl][1] = pack2(acc[kt][jl][2], acc[kt][jl][3]);
        }
    const int srcL[2] = { (m15 + 16 * (2 * (g4 & 1) + 0)) << 2,
                          (m15 + 16 * (2 * (g4 & 1) + 1)) << 2 };
    const bool hiHalf = (g4 >> 1) != 0;
    bf16x8 afr[3][3];
    #pragma unroll
    for (int jl = 0; jl < 3; ++jl)
        #pragma unroll
        for (int kk = 0; kk < 3; ++kk) {
            u32x4 w;
            #pragma unroll
            for (int p = 0; p < 4; ++p) {
                int va = __builtin_amdgcn_ds_bpermute(srcL[p >> 1], (int)pk[2 * kk][jl][p & 1]);
                int vb = __builtin_amdgcn_ds_bpermute(srcL[p >> 1], (int)pk[2 * kk + 1][jl][p & 1]);
                w[p] = (unsigned)(hiHalf ? vb : va);
            }
            afr[jl][kk] = __builtin_bit_cast(bf16x8, w);
        }

    // hty publish: accY[kt][r] (same on every m15) -> htyL[kt*16 + g4*4 + r]
    if (wid == 0 && m15 == 0) {
        #pragma unroll
        for (int kt = 0; kt < 6; ++kt)
            #pragma unroll
            for (int r = 0; r < 4; ++r)
                htyL[kt * 16 + g4 * 4 + r] = accY[kt][r];
    }

    // ================= Phase B init =================
    const bool wr = (m15 < 3);
    const int  rb = wid * 48 + m15 * 16 + g4 * 4;   // writer's 4 rows
    float yx4[4] = {0, 0, 0, 0}, xc4[4] = {0, 0, 0, 0}, hty4[4] = {0, 0, 0, 0};
    if (wr) {
        float4 xi = *(const float4*)(x_ini + (size_t)b * NN + rb);
        yx4[0] = xi.x; yx4[1] = xi.y; yx4[2] = xi.z; yx4[3] = xi.w;
        xc4[0] = xi.x; xc4[1] = xi.y; xc4[2] = xi.z; xc4[3] = xi.w;
        yxD[0][(rb >> 1) + 0] = pack2(yx4[0], yx4[1]);
        yxD[0][(rb >> 1) + 1] = pack2(yx4[2], yx4[3]);
    }
    __syncthreads();   // htyL + yxD[0] visible
    if (wr) {
        float4 ht = *(const float4*)&htyL[rb];
        hty4[0] = ht.x; hty4[1] = ht.y; hty4[2] = ht.z; hty4[3] = ht.w;
    }

    // ================= Phase B: 20 iterations, 1 barrier each =================
    int cur = 0;
    for (int t = 0; t < LL; ++t) {
        bf16x8 bf[3];
        #pragma unroll
        for (int kk = 0; kk < 3; ++kk)
            bf[kk] = *(const bf16x8*)&yxD[cur][kk * 16 + g4 * 4];
        f32x4 aD[3];
        #pragma unroll
        for (int jl = 0; jl < 3; ++jl)
            #pragma unroll
            for (int r = 0; r < 4; ++r) aD[jl][r] = 0.f;
        #pragma unroll
        for (int kk = 0; kk < 3; ++kk)
            #pragma unroll
            for (int jl = 0; jl < 3; ++jl)
                aD[jl] = __builtin_amdgcn_mfma_f32_16x16x32_bf16(afr[jl][kk], bf[kk], aD[jl], 0, 0, 0);
        f32x4 am = aD[0];
        am = (m15 == 1) ? aD[1] : am;
        am = (m15 == 2) ? aD[2] : am;

        if (wr) {
            const float gs = par[0][t], es = par[1][t], gmv = par[2][t];
            #pragma unroll
            for (int r = 0; r < 4; ++r) {
                float xb  = fmaf(-2.0f * gs, am[r] - hty4[r], yx4[r]);
                float cen = 2.0f * fminf(fmaxf(rintf(xb * 0.5f), -1.0f), 1.0f);
                float z   = gmv * (xb - cen);
                float e   = __expf(-z);
                float ply = fmaf(2.0f, __builtin_amdgcn_rcpf(1.0f + e), -1.0f);
                float yxn = fmaf(es, ply - xc4[r], ply);
                xc4[r] = ply;
                yx4[r] = yxn;
            }
            if (t + 1 < LL) {
                yxD[cur ^ 1][(rb >> 1) + 0] = pack2(yx4[0], yx4[1]);
                yxD[cur ^ 1][(rb >> 1) + 1] = pack2(yx4[2], yx4[3]);
            }
        }
        __syncthreads();
        cur ^= 1;
    }

    // ================= epilogue =================
    float part = 0.f;
    if (wr) {
        float4 xo;
        xo.x = xc4[0]; xo.y = xc4[1]; xo.z = xc4[2]; xo.w = xc4[3];
        *(float4*)(out + (size_t)b * NN + rb) = xo;
        float4 xr = *(const float4*)(xt + (size_t)b * NN + rb);
        float d0 = xc4[0] - xr.x, d1 = xc4[1] - xr.y;
        float d2 = xc4[2] - xr.z, d3 = xc4[3] - xr.w;
        part = (d0 * d0 + d1 * d1) + (d2 * d2 + d3 * d3);
    }
    #pragma unroll
    for (int m = 1; m < 64; m <<= 1) part += __shfl_xor(part, m, 64);
    if (lane == 0) atomicAdd(out + (size_t)NB * NN, part);
}

extern "C" void kernel_launch(void* const* d_in, const int* in_sizes, int n_in,
                              void* d_out, int out_size, void* d_ws, size_t ws_size,
                              hipStream_t stream) {
    const float* x_ini    = (const float*)d_in[0];
    const float* y        = (const float*)d_in[1];
    const float* H        = (const float*)d_in[2];
    const float* xt       = (const float*)d_in[3];
    const float* grad_ss  = (const float*)d_in[4];
    const float* extra_ss = (const float*)d_in[5];
    const float* gamma1   = (const float*)d_in[6];
    float* out = (float*)d_out;

    hipMemsetAsync(out + (size_t)NB * NN, 0, sizeof(float), stream);
    pg_kernel<<<NB, 128, 0, stream>>>(x_ini, y, H, xt, grad_ss, extra_ss, gamma1, out);
}